// Round 1
// baseline (586.918 us; speedup 1.0000x reference)
//
#include <hip/hip_runtime.h>
#include <math.h>

#define TT 256
#define FF 64
#define HH 20
#define G4 80   // 4*H
#define EPB 4   // batch elems per block
#define BLK 320 // 4 * 80 threads

__device__ __forceinline__ float sigmoidf_(float z) {
    return 1.0f / (1.0f + __expf(-z));
}

// thread = (elem, j) with j = u*4 + g; column in [F,4H] weights is col = g*20 + u.
// Gate quad (u fixed, g=0..3) is 4-aligned in lane space -> __shfl_xor combine.
// Weights held in per-thread registers (124 VGPRs); x/h shared via LDS broadcast.
__global__ __launch_bounds__(BLK, 2) void lstm2_fused(
    const float* __restrict__ x,
    const float* __restrict__ W1, const float* __restrict__ U1, const float* __restrict__ b1,
    const float* __restrict__ W2, const float* __restrict__ U2, const float* __restrict__ b2,
    const float* __restrict__ Wd, const float* __restrict__ bd,
    float* __restrict__ out)
{
    const int tid  = threadIdx.x;
    const int elem = tid / G4;          // 0..3
    const int j    = tid - elem * G4;   // 0..79
    const int u    = j >> 2;            // hidden unit 0..19
    const int g    = j & 3;             // gate: 0=i 1=f 2=g 3=o
    const int col  = g * HH + u;        // weight column
    const int b0   = blockIdx.x * EPB;

    __shared__ float xs[2][EPB][FF];    // x tile, double buffered
    __shared__ float h1b[2][EPB][24];   // h1 (padded to 24 for float4 rows)
    __shared__ float h2b[2][EPB][24];

    // ---- load this thread's weight columns into registers ----
    float w1[FF];
#pragma unroll
    for (int f = 0; f < FF; ++f) w1[f] = W1[f * G4 + col];
    float u1[HH], w2[HH], u2[HH];
#pragma unroll
    for (int k = 0; k < HH; ++k) u1[k] = U1[k * G4 + col];
#pragma unroll
    for (int k = 0; k < HH; ++k) w2[k] = W2[k * G4 + col];
#pragma unroll
    for (int k = 0; k < HH; ++k) u2[k] = U2[k * G4 + col];
    const float bias1 = b1[col];
    const float bias2 = b2[col];

    // ---- init LDS ----
    for (int i = tid; i < 2 * EPB * 24; i += BLK) ((float*)h1b)[i] = 0.f;
    for (int i = tid; i < 2 * EPB * 24; i += BLK) ((float*)h2b)[i] = 0.f;
    if (tid < EPB * FF) {
        int e2 = tid >> 6, f2 = tid & 63;
        xs[0][e2][f2] = x[((long)(b0 + e2) * TT + 0) * FF + f2];
    }
    __syncthreads();

    float c1 = 0.f, c2 = 0.f;  // cell state (meaningful in g==0 lanes)

    for (int t = 0; t < TT; ++t) {
        const int cur = t & 1;

        // prefetch next timestep's x into registers
        float xpre = 0.f;
        const int t2 = t + 1;
        if (t2 < TT && tid < EPB * FF) {
            int e2 = tid >> 6, f2 = tid & 63;
            xpre = x[((long)(b0 + e2) * TT + t2) * FF + f2];
        }

        // ---------------- layer 1: z = b1 + x@W1 + h1@U1 ----------------
        float z = bias1;
        const float4* xv = (const float4*)xs[cur][elem];
#pragma unroll
        for (int q = 0; q < FF / 4; ++q) {
            float4 xx = xv[q];
            z = fmaf(xx.x, w1[4*q+0], z);
            z = fmaf(xx.y, w1[4*q+1], z);
            z = fmaf(xx.z, w1[4*q+2], z);
            z = fmaf(xx.w, w1[4*q+3], z);
        }
        const float4* hv = (const float4*)h1b[cur][elem];
#pragma unroll
        for (int q = 0; q < HH / 4; ++q) {
            float4 hh = hv[q];
            z = fmaf(hh.x, u1[4*q+0], z);
            z = fmaf(hh.y, u1[4*q+1], z);
            z = fmaf(hh.z, u1[4*q+2], z);
            z = fmaf(hh.w, u1[4*q+3], z);
        }
        // gather the quad's 4 gate pre-activations into the g==0 lane
        float s1 = __shfl_xor(z, 1);
        float s2 = __shfl_xor(z, 2);
        float s3 = __shfl_xor(z, 3);
        // valid only in g==0 lanes (others compute garbage, unused)
        float ig = sigmoidf_(z);
        float fg = sigmoidf_(s1);
        float gg = fmaxf(s2, 0.f);
        float og = sigmoidf_(s3);
        c1 = fg * c1 + ig * gg;
        float h1n = og * fmaxf(c1, 0.f);
        if (g == 0) h1b[cur ^ 1][elem][u] = h1n;
        __syncthreads();   // h1(t) visible; xs[cur]/h1b[cur] reads complete

        // write prefetched x into the other buffer
        if (t2 < TT && tid < EPB * FF) {
            xs[cur ^ 1][tid >> 6][tid & 63] = xpre;
        }

        // ---------------- layer 2: z2 = b2 + h1(t)@W2 + h2@U2 ----------------
        float z2 = bias2;
        const float4* h1v = (const float4*)h1b[cur ^ 1][elem];  // h1(t)
        const float4* h2v = (const float4*)h2b[cur][elem];      // h2(t-1)
#pragma unroll
        for (int q = 0; q < HH / 4; ++q) {
            float4 ha = h1v[q];
            float4 hb = h2v[q];
            z2 = fmaf(ha.x, w2[4*q+0], z2);
            z2 = fmaf(ha.y, w2[4*q+1], z2);
            z2 = fmaf(ha.z, w2[4*q+2], z2);
            z2 = fmaf(ha.w, w2[4*q+3], z2);
            z2 = fmaf(hb.x, u2[4*q+0], z2);
            z2 = fmaf(hb.y, u2[4*q+1], z2);
            z2 = fmaf(hb.z, u2[4*q+2], z2);
            z2 = fmaf(hb.w, u2[4*q+3], z2);
        }
        s1 = __shfl_xor(z2, 1);
        s2 = __shfl_xor(z2, 2);
        s3 = __shfl_xor(z2, 3);
        ig = sigmoidf_(z2);
        fg = sigmoidf_(s1);
        gg = fmaxf(s2, 0.f);
        og = sigmoidf_(s3);
        c2 = fg * c2 + ig * gg;
        float h2n = og * fmaxf(c2, 0.f);
        if (g == 0) h2b[cur ^ 1][elem][u] = h2n;
        __syncthreads();   // h2(t) + xs[cur^1] visible
    }

    // ---------------- dense head: out[b] = h2(T-1) @ Wd + bd ----------------
    // t=255: cur=1, final h2 written to h2b[0]
    if (j == 0) {
        float acc = bd[0];
#pragma unroll
        for (int k = 0; k < HH; ++k) acc += h2b[0][elem][k] * Wd[k];
        out[b0 + elem] = acc;
    }
}

extern "C" void kernel_launch(void* const* d_in, const int* in_sizes, int n_in,
                              void* d_out, int out_size, void* d_ws, size_t ws_size,
                              hipStream_t stream) {
    const float* x  = (const float*)d_in[0];
    const float* W1 = (const float*)d_in[1];
    const float* U1 = (const float*)d_in[2];
    const float* b1 = (const float*)d_in[3];
    const float* W2 = (const float*)d_in[4];
    const float* U2 = (const float*)d_in[5];
    const float* b2 = (const float*)d_in[6];
    const float* Wd = (const float*)d_in[7];
    const float* bd = (const float*)d_in[8];
    float* out = (float*)d_out;
    const int B = in_sizes[0] / (TT * FF);   // 2048
    dim3 grid(B / EPB), block(BLK);
    hipLaunchKernelGGL(lstm2_fused, grid, block, 0, stream,
                       x, W1, U1, b1, W2, U2, b2, Wd, bd, out);
}